// Round 6
// baseline (3452.871 us; speedup 1.0000x reference)
//
#include <hip/hip_runtime.h>
#include <cfloat>
#include <math.h>

#define NOBS   256
#define NY     50
#define NX     30
#define NITER  400
#define LRATE  0.05f
#define THRANK 40      // persisted theta tracks the rank-40 element (aN <= 25.6 always)

__device__ __forceinline__ float rl_f(float x, int k) {
  // v_readlane: SGPR broadcast, no DS-pipe traffic
  return __int_as_float(__builtin_amdgcn_readlane(__float_as_int(x), k));
}

// wave64 max: row_shr 1,2,4,8 + row_bcast 15,31; old=x keeps invalid lanes at identity.
#define DPP_MAXSTEP(x, ctrl)                                                       \
  x = fmaxf(x, __int_as_float(__builtin_amdgcn_update_dpp(                         \
        __float_as_int(x), __float_as_int(x), (ctrl), 0xF, 0xF, false)))

// wave64 sum, result valid in lane 63: old=0, bound_ctrl=1 -> invalid lanes add 0.
__device__ __forceinline__ float wsum63(float x) {
#define SUMSTEP(ctrl)                                                              \
  x += __int_as_float(__builtin_amdgcn_update_dpp(                                 \
         0, __float_as_int(x), (ctrl), 0xF, 0xF, true))
  SUMSTEP(0x111); SUMSTEP(0x112); SUMSTEP(0x114); SUMSTEP(0x118);  // row_shr 1,2,4,8
  SUMSTEP(0x142); SUMSTEP(0x143);                                  // row_bcast 15,31
#undef SUMSTEP
  return x;
}

// One wave64 per scenario: ALL sync is intra-wave (no s_barrier anywhere).
// 64-thread block + waves_per_eu(1,1): 512-reg budget so er[4][50] stays in registers.
__global__ __launch_bounds__(64) __attribute__((amdgpu_waves_per_eu(1, 1)))
void dro_kernel(
    const float* __restrict__ X, const float* __restrict__ Y,
    const float* __restrict__ W, const float* __restrict__ Bb,
    const float* __restrict__ DLT, const float* __restrict__ GMM,
    float* __restrict__ out)
{
  __shared__ __align__(16) float ep_l[NOBS * 52];              // init staging only (53 KB)
  __shared__ __align__(16) unsigned long long rrk[NOBS];       // full keys (fallback scan)
  __shared__ __align__(16) unsigned long long ckey[320];       // candidates + sentinel pads
  __shared__ __align__(16) float gvec[64];                     // reduced gradient vector

  const int lane = threadIdx.x;     // 0..63, single wave
  const int t    = blockIdx.x;      // scenario

  const float delta = DLT[0];
  const float gamma = GMM[0];
  const float a     = fminf(delta * 0.5f, 255.0f / 256.0f);
  const float a256  = a * 256.0f;

  // ---- init: residuals for obs 4*lane+q staged via LDS (keeps init code small) ----
  for (int q = 0; q < 4; ++q) {
    const int o = 4 * lane + q;
    float xr[NX];
    #pragma unroll
    for (int k = 0; k < NX; ++k) xr[k] = X[o * NX + k];
    for (int j = 0; j < NY; ++j) {                   // rolled; W/B uniform -> scalar loads
      float acc = Bb[j];
      #pragma unroll
      for (int k = 0; k < NX; ++k) acc = fmaf(xr[k], W[j * NX + k], acc);
      ep_l[o * 52 + j] = Y[o * NY + j] - acc;
    }
  }
  // y_hat for this scenario: lane j computes row t, col j
  float yhl;
  {
    const int jr = (lane < NY) ? lane : 0;           // clamp to avoid OOB W reads
    float acc = Bb[jr];
    #pragma unroll
    for (int k = 0; k < NX; ++k) acc = fmaf(X[t * NX + k], W[jr * NX + k], acc);
    yhl = acc;
    if (lane < NY) out[NOBS * NY + t * NY + lane] = acc;
  }
  // LDS -> registers: er[q][0..49] (elements 50/51 loaded but dead)
  float er0[52], er1[52], er2[52], er3[52];
  #pragma unroll
  for (int i = 0; i < 13; ++i) {
    float4 v0 = *(const float4*)&ep_l[(4 * lane + 0) * 52 + 4 * i];
    float4 v1 = *(const float4*)&ep_l[(4 * lane + 1) * 52 + 4 * i];
    float4 v2 = *(const float4*)&ep_l[(4 * lane + 2) * 52 + 4 * i];
    float4 v3 = *(const float4*)&ep_l[(4 * lane + 3) * 52 + 4 * i];
    er0[4*i]=v0.x; er0[4*i+1]=v0.y; er0[4*i+2]=v0.z; er0[4*i+3]=v0.w;
    er1[4*i]=v1.x; er1[4*i+1]=v1.y; er1[4*i+2]=v1.z; er1[4*i+3]=v1.w;
    er2[4*i]=v2.x; er2[4*i+1]=v2.y; er2[4*i+2]=v2.z; er2[4*i+3]=v2.w;
    er3[4*i]=v3.x; er3[4*i+1]=v3.y; er3[4*i+2]=v3.z; er3[4*i+3]=v3.w;
  }

  float zv    = (lane < NY) ? (1.0f / NY) : 0.0f;    // z: one entry per lane
  float cc    = 0.0f;                                // c (wave-uniform)
  float theta = FLT_MAX;                             // candidate threshold (wave-uniform)

  #pragma unroll 1
  for (int it = 0; it < NITER; ++it) {
    // ---- forward: u_q = er_q . z - c (z broadcast via readlane; 4-way ILP) ----
    float u0 = 0.f, u1 = 0.f, u2 = 0.f, u3 = 0.f;
    #pragma unroll
    for (int j = 0; j < NY; ++j) {
      const float zj = rl_f(zv, j);
      u0 = fmaf(er0[j], zj, u0);
      u1 = fmaf(er1[j], zj, u1);
      u2 = fmaf(er2[j], zj, u2);
      u3 = fmaf(er3[j], zj, u3);
    }
    u0 -= cc; u1 -= cc; u2 -= cc; u3 -= cc;
    const float r0 = u0 * u0, r1 = u1 * u1, r2 = u2 * u2, r3 = u3 * u3;

    // stable keys (r>=0: float bits order-isomorphic; low 32 = obs index)
    const unsigned base = 4u * (unsigned)lane;
    const unsigned long long k0 = ((unsigned long long)(unsigned)__float_as_int(r0) << 32) | (base + 0);
    const unsigned long long k1 = ((unsigned long long)(unsigned)__float_as_int(r1) << 32) | (base + 1);
    const unsigned long long k2 = ((unsigned long long)(unsigned)__float_as_int(r2) << 32) | (base + 2);
    const unsigned long long k3 = ((unsigned long long)(unsigned)__float_as_int(r3) << 32) | (base + 3);
    rrk[base + 0] = k0; rrk[base + 1] = k1; rrk[base + 2] = k2; rrk[base + 3] = k3;

    // global max of all 256 r's
    float m = fmaxf(fmaxf(r0, r1), fmaxf(r2, r3));
    DPP_MAXSTEP(m, 0x111); DPP_MAXSTEP(m, 0x112);
    DPP_MAXSTEP(m, 0x114); DPP_MAXSTEP(m, 0x118);
    DPP_MAXSTEP(m, 0x142); DPP_MAXSTEP(m, 0x143);
    const float mx = rl_f(m, 63);
    const bool im0 = (r0 == mx), im1 = (r1 == mx), im2 = (r2 == mx), im3 = (r3 == mx);
    const int cm = __popcll(__ballot(im0)) + __popcll(__ballot(im1)) +
                   __popcll(__ballot(im2)) + __popcll(__ballot(im3));
    const float amax = a / (float)cm;                // max-tie share (uniform)

    // candidate filter + compaction (slot-major order; set membership is all that matters)
    const bool cd0 = (r0 < theta), cd1 = (r1 < theta), cd2 = (r2 < theta), cd3 = (r3 < theta);
    const unsigned long long b0 = __ballot(cd0), b1 = __ballot(cd1),
                             b2 = __ballot(cd2), b3 = __ballot(cd3);
    const int C0 = __popcll(b0), C1 = __popcll(b1), C2 = __popcll(b2), C3 = __popcll(b3);
    const int C  = C0 + C1 + C2 + C3;
    const unsigned long long ml = (1ull << lane) - 1ull;
    if (cd0) ckey[__popcll(b0 & ml)] = k0;
    if (cd1) ckey[C0 + __popcll(b1 & ml)] = k1;
    if (cd2) ckey[C0 + C1 + __popcll(b2 & ml)] = k2;
    if (cd3) ckey[C0 + C1 + C2 + __popcll(b3 & ml)] = k3;
    ckey[C + lane] = ~0ull;                          // sentinels cover [C, C+64)

    // ---- exact stable ranks ----
    int c0, c1, c2, c3;
    const bool valid = ((float)C >= a256) && (C <= 64);
    if (__builtin_expect(valid, 1)) {
      // candidates get exact global rank; non-candidates count all C candidates
      // below them -> cnt=C>=aN -> gfac=1/N automatically. Sentinels contribute 0.
      c0 = c1 = c2 = c3 = 0;
      const ulonglong2* ck2 = (const ulonglong2*)&ckey[0];
      #pragma unroll
      for (int j = 0; j < 32; ++j) {
        const ulonglong2 kk = ck2[j];
        c0 += (kk.x < k0); c0 += (kk.y < k0);
        c1 += (kk.x < k1); c1 += (kk.y < k1);
        c2 += (kk.x < k2); c2 += (kk.y < k2);
        c3 += (kk.x < k3); c3 += (kk.y < k3);
      }
    } else {                                         // iter 0 / drift: exact full scan
      c0 = c1 = c2 = c3 = 0;
      const ulonglong2* rk2 = (const ulonglong2*)&rrk[0];
      #pragma unroll 2
      for (int j = 0; j < 128; ++j) {
        const ulonglong2 kk = rk2[j];
        c0 += (kk.x < k0); c0 += (kk.y < k0);
        c1 += (kk.x < k1); c1 += (kk.y < k1);
        c2 += (kk.x < k2); c2 += (kk.y < k2);
        c3 += (kk.x < k3); c3 += (kk.y < k3);
      }
    }

    // theta <- value at rank THRANK (guard to candidate slots when filtered:
    // non-candidates all carry cnt=C and would false-match when C==THRANK)
    {
      const unsigned long long e0 = __ballot((c0 == THRANK) && (!valid || cd0));
      const unsigned long long e1 = __ballot((c1 == THRANK) && (!valid || cd1));
      const unsigned long long e2 = __ballot((c2 == THRANK) && (!valid || cd2));
      const unsigned long long e3 = __ballot((c3 == THRANK) && (!valid || cd3));
      if (e0) theta = rl_f(r0, __builtin_ctzll(e0));
      if (e1) theta = rl_f(r1, __builtin_ctzll(e1));
      if (e2) theta = rl_f(r2, __builtin_ctzll(e2));
      if (e3) theta = rl_f(r3, __builtin_ctzll(e3));
    }

    // g_i = (1/N) clamp(rank+1-aN, 0, 1) + a*[tied max]/#ties ; coef = 2 u g
    const float g0 = fminf(fmaxf((float)c0 + 1.0f - a256, 0.0f), 1.0f) * (1.0f/256.0f) + (im0 ? amax : 0.0f);
    const float g1 = fminf(fmaxf((float)c1 + 1.0f - a256, 0.0f), 1.0f) * (1.0f/256.0f) + (im1 ? amax : 0.0f);
    const float g2 = fminf(fmaxf((float)c2 + 1.0f - a256, 0.0f), 1.0f) * (1.0f/256.0f) + (im2 ? amax : 0.0f);
    const float g3 = fminf(fmaxf((float)c3 + 1.0f - a256, 0.0f), 1.0f) * (1.0f/256.0f) + (im3 ? amax : 0.0f);
    const float f0 = 2.0f * u0 * g0, f1 = 2.0f * u1 * g1,
                f2 = 2.0f * u2 * g2, f3 = 2.0f * u3 * g3;

    // ---- backward from REGISTERS: p_j = sum_q coef_q * er_q[j]; DPP wave-sum ----
    #pragma unroll
    for (int j = 0; j < NY; ++j) {
      float p = f0 * er0[j];
      p = fmaf(f1, er1[j], p);
      p = fmaf(f2, er2[j], p);
      p = fmaf(f3, er3[j], p);
      const float s = wsum63(p);
      if (lane == 63) gvec[j] = s;                   // single-lane scatter
    }
    {
      const float s = wsum63((f0 + f1) + (f2 + f3)); // sum(coef) -> c gradient
      if (lane == 63) gvec[NY] = s;
    }

    // ---- step + counting-method simplex projection (all intra-wave) ----
    const float s4 = gvec[lane];                     // lane j gets grad_j; lane 50 = sum(coef)
    cc = cc + LRATE * rl_f(s4, NY);                  // gc = -sum(coef)
    const float gz = s4 - gamma * yhl;
    const float v  = zv - LRATE * gz;

    int ahead = 0; float cs0 = 0.f, cs1 = 0.f;
    #pragma unroll
    for (int k = 0; k < NY; k += 2) {
      const float vk0 = rl_f(v, k);
      const float vk1 = rl_f(v, k + 1);
      const bool a0 = (vk0 > v) || (vk0 == v && (k    ) > lane);
      const bool a1 = (vk1 > v) || (vk1 == v && (k + 1) > lane);
      ahead += (a0 ? 1 : 0) + (a1 ? 1 : 0);
      cs0 += a0 ? vk0 : 0.0f;
      cs1 += a1 ? vk1 : 0.0f;
    }
    const float css = (cs0 + cs1) + v - 1.0f;
    const bool pc = (lane < NY) && (v - css / (float)(ahead + 1) > 0.0f);
    const int rho = __popcll(__ballot(pc));          // >= 1 always
    const unsigned long long bsel = __ballot((lane < NY) && (ahead == rho - 1));
    const int srcl = __ffsll(bsel) - 1;
    const float tau =
        __int_as_float(__builtin_amdgcn_readlane(__float_as_int(css), srcl)) / (float)rho;
    zv = (lane < NY) ? fmaxf(v - tau, 0.0f) : 0.0f;
  }

  if (lane < NY) out[t * NY + lane] = zv;
}

extern "C" void kernel_launch(void* const* d_in, const int* in_sizes, int n_in,
                              void* d_out, int out_size, void* d_ws, size_t ws_size,
                              hipStream_t stream) {
  (void)in_sizes; (void)n_in; (void)d_ws; (void)ws_size; (void)out_size;
  const float* X   = (const float*)d_in[0];
  const float* Y   = (const float*)d_in[1];
  const float* W   = (const float*)d_in[2];
  const float* B   = (const float*)d_in[3];
  const float* DLT = (const float*)d_in[4];
  const float* GMM = (const float*)d_in[5];
  float* out = (float*)d_out;
  hipLaunchKernelGGL(dro_kernel, dim3(NOBS), dim3(64), 0, stream,
                     X, Y, W, B, DLT, GMM, out);
}

// Round 7
// 2301.715 us; speedup vs baseline: 1.5001x; 1.5001x over previous
//
#include <hip/hip_runtime.h>
#include <cfloat>
#include <math.h>

#define NOBS   256
#define NY     50
#define NX     30
#define NITER  400
#define LRATE  0.05f
#define CSTR   260     // ep_t column stride (floats)
#define THRANK 40      // persisted theta tracks the rank-40 element (aN <= 25.6 always)

__device__ __forceinline__ float rl_f(float x, int k) {
  // v_readlane: SGPR broadcast, no DS-pipe traffic
  return __int_as_float(__builtin_amdgcn_readlane(__float_as_int(x), k));
}

// wave64 max: row_shr 1,2,4,8 + row_bcast 15,31; old=x keeps invalid lanes at identity.
// Result valid in lane 63.
#define DPP_MAXSTEP(x, ctrl)                                                       \
  x = fmaxf(x, __int_as_float(__builtin_amdgcn_update_dpp(                         \
        __float_as_int(x), __float_as_int(x), (ctrl), 0xF, 0xF, false)))

// One scenario per block, split across 8 waves (2 per SIMD -> latency overlap on ALL CUs).
// Thread tid owns obs (tid&255); half A (waves 0-3) holds er[0:25), half B er[25:50).
// waves_per_eu(2,2): exactly-2 occupancy target -> 256-VGPR budget, no spill (R4 lesson).
__global__ __launch_bounds__(512) __attribute__((amdgpu_waves_per_eu(2, 2)))
void dro_kernel(
    const float* __restrict__ X, const float* __restrict__ Y,
    const float* __restrict__ W, const float* __restrict__ Bb,
    const float* __restrict__ DLT, const float* __restrict__ GMM,
    float* __restrict__ out)
{
  __shared__ __align__(16) float ep_t[51 * CSTR];          // 53040 B, column-major (+ones col)
  __shared__ __align__(16) unsigned long long rrk[NOBS];   // full keys (fallback scan)
  __shared__ __align__(16) unsigned long long ckey[320];   // compacted candidates + sentinels
  __shared__ __align__(16) float pex[512];                 // forward half-dot exchange
  __shared__ __align__(16) int   cex[512];                 // rank half-count exchange
  __shared__ __align__(16) float red8[8 * 64];             // 8 per-wave backward partials
  __shared__ float wmax4[4];
  __shared__ int   ccnt[4];
  __shared__ int   wcnt[4];
  __shared__ float sh_theta;

  const int tid  = threadIdx.x;      // 0..511
  const int oid  = tid & 255;        // owned observation
  const int half = tid >> 8;         // 0 = A (j 0..24), 1 = B (j 25..49)
  const int lane = tid & 63;
  const int w8   = tid >> 6;         // wave 0..7
  const int wsc  = w8 & 3;           // obs-coverage wave (obs base wsc*64)
  const int t    = blockIdx.x;       // scenario
  const int jbase = half * 25;

  const float delta = DLT[0];
  const float gamma = GMM[0];
  const float a     = fminf(delta * 0.5f, 255.0f / 256.0f);
  const float a256  = a * 256.0f;

  // ---- init: each thread computes its 25-column slice of its obs row ----
  float er[25];
  {
    float xr[NX];
    #pragma unroll
    for (int k = 0; k < NX; ++k) xr[k] = X[oid * NX + k];
    for (int jj = 0; jj < 25; ++jj) {              // W/B indices wave-uniform -> scalar loads
      const int j = jbase + jj;
      float acc = Bb[j];
      #pragma unroll
      for (int k = 0; k < NX; ++k) acc = fmaf(xr[k], W[j * NX + k], acc);
      const float e = Y[oid * NY + j] - acc;
      er[jj] = e;
      ep_t[j * CSTR + oid] = e;                    // column-major
    }
    if (half == 1) ep_t[NY * CSTR + oid] = 1.0f;   // ones column -> c gradient
  }
  // y_hat row t: per-lane copy (every wave computes; wave 0 stores)
  float yhl;
  {
    const int jr = (lane < NY) ? lane : 0;
    float acc = Bb[jr];
    #pragma unroll
    for (int k = 0; k < NX; ++k) acc = fmaf(X[t * NX + k], W[jr * NX + k], acc);
    yhl = acc;
    if (tid < NY) out[NOBS * NY + t * NY + tid] = acc;
  }
  if (tid == 0) sh_theta = FLT_MAX;                // iter 0: all candidates -> exact fallback
  __syncthreads();

  float zv = (lane < NY) ? (1.0f / NY) : 0.0f;     // z one entry/lane, replicated per wave
  float cc = 0.0f;                                 // c, wave-uniform (identical in all waves)

  #pragma unroll 1
  for (int it = 0; it < NITER; ++it) {
    // ---- phase 0: forward HALF-dot (25 terms; z via readlane) ----
    const float theta = sh_theta;                  // written post-B4 prev iter; B5 separates
    float a0 = 0.f, a1 = 0.f, a2 = 0.f, a3 = 0.f;
    #pragma unroll
    for (int jj = 0; jj < 24; jj += 4) {
      a0 = fmaf(er[jj + 0], rl_f(zv, jbase + jj + 0), a0);
      a1 = fmaf(er[jj + 1], rl_f(zv, jbase + jj + 1), a1);
      a2 = fmaf(er[jj + 2], rl_f(zv, jbase + jj + 2), a2);
      a3 = fmaf(er[jj + 3], rl_f(zv, jbase + jj + 3), a3);
    }
    a0 = fmaf(er[24], rl_f(zv, jbase + 24), a0);
    pex[tid] = (a0 + a2) + (a1 + a3);
    __syncthreads();                               // B1: pex

    // ---- phase 1: combine halves -> u, r, key; wave max; candidate ballot ----
    // A and B threads for obs oid evaluate the SAME expression on the SAME LDS
    // values in the same order -> bitwise-identical u/r/key across the pair.
    const float u = (pex[oid] + pex[256 + oid]) - cc;
    const float r = u * u;
    const unsigned long long key =
        ((unsigned long long)(unsigned)__float_as_int(r) << 32) | (unsigned)oid;
    if (half == 0) rrk[oid] = key;

    float m = r;                                   // wave max via DPP (A waves cover all obs)
    DPP_MAXSTEP(m, 0x111); DPP_MAXSTEP(m, 0x112);
    DPP_MAXSTEP(m, 0x114); DPP_MAXSTEP(m, 0x118);
    DPP_MAXSTEP(m, 0x142); DPP_MAXSTEP(m, 0x143);
    if (w8 < 4 && lane == 63) wmax4[wsc] = m;

    const bool cond = (r < theta);
    const unsigned long long cmask = __ballot(cond);
    const int cpos = __popcll(cmask & ((1ull << lane) - 1ull));
    if (w8 < 4 && lane == 0) ccnt[wsc] = __popcll(cmask);
    __syncthreads();                               // B2: rrk, wmax4, ccnt

    // ---- phase 2: compaction (A only) + sentinels + max-tie count ----
    const int c0 = ccnt[0], c1 = ccnt[1], c2 = ccnt[2], c3 = ccnt[3];
    const int C  = c0 + c1 + c2 + c3;
    if (half == 0) {
      const int coff = (wsc > 0 ? c0 : 0) + (wsc > 1 ? c1 : 0) + (wsc > 2 ? c2 : 0);
      if (cond) ckey[coff + cpos] = key;
    }
    if (tid < 64) ckey[C + tid] = ~0ull;           // sentinels cover [C, C+64)

    const float mx = fmaxf(fmaxf(wmax4[0], wmax4[1]), fmaxf(wmax4[2], wmax4[3]));
    const bool ismax = (r == mx);
    const unsigned long long mmask = __ballot(ismax);  // all lanes (R3 lesson)
    if (w8 < 4 && lane == 0) wcnt[wsc] = __popcll(mmask);
    __syncthreads();                               // B3: ckey, wcnt

    // ---- phase 3: HALF rank-scan (A slots [0,32), B [32,64); fallback halves rrk) ----
    const bool valid = ((float)C >= a256) && (C <= 64);
    int ch = 0;
    if (__builtin_expect(valid, 1)) {
      const ulonglong2* p = (const ulonglong2*)&ckey[half * 32];
      #pragma unroll
      for (int j = 0; j < 16; ++j) {
        const ulonglong2 kk = p[j];
        ch += (kk.x < key) ? 1 : 0;
        ch += (kk.y < key) ? 1 : 0;
      }
    } else {                                       // iter 0 / drift: exact full scan, halved
      const ulonglong2* p = (const ulonglong2*)&rrk[half * 128];
      #pragma unroll 8
      for (int j = 0; j < 64; ++j) {
        const ulonglong2 kk = p[j];
        ch += (kk.x < key) ? 1 : 0;
        ch += (kk.y < key) ? 1 : 0;
      }
    }
    cex[tid] = ch;
    const int cm = wcnt[0] + wcnt[1] + wcnt[2] + wcnt[3];
    __syncthreads();                               // B4: cex

    // ---- phase 4: total rank -> g, coef; split backward (32 obs per wave) ----
    const int cnt = cex[oid] + cex[256 + oid];     // exact global stable rank
    if (half == 0 && cnt == THRANK && (!valid || cond)) sh_theta = r;  // single writer
    // g_i = (1/N) clamp(rank+1-aN, 0, 1) + a*[tied max]/#ties
    const float gfac  = fminf(fmaxf((float)cnt + 1.0f - a256, 0.0f), 1.0f) * (1.0f / 256.0f);
    const float g     = gfac + (ismax ? (a / (float)cm) : 0.0f);
    const float coefv = 2.0f * u * g;

    // wave w8 handles obs [wsc*64 + half*32, +32): its own lanes lbase..lbase+31 hold their coef
    const int obase = wsc * 64 + half * 32;
    const int lbase = half * 32;
    const int col   = (lane < 51) ? lane : 50;
    const float4* eb = (const float4*)&ep_t[col * CSTR + obase];
    float q0 = 0.f, q1 = 0.f, q2 = 0.f, q3 = 0.f;
    #pragma unroll
    for (int q = 0; q < 8; ++q) {
      const float4 e4 = eb[q];
      q0 = fmaf(rl_f(coefv, lbase + 4 * q + 0), e4.x, q0);
      q1 = fmaf(rl_f(coefv, lbase + 4 * q + 1), e4.y, q1);
      q2 = fmaf(rl_f(coefv, lbase + 4 * q + 2), e4.z, q2);
      q3 = fmaf(rl_f(coefv, lbase + 4 * q + 3), e4.w, q3);
    }
    red8[w8 * 64 + lane] = (q0 + q2) + (q1 + q3);
    __syncthreads();                               // B5: red8, sh_theta

    // ---- phase 5: sum 8 partials; step + counting-method projection (per-wave) ----
    const float s4 = ((red8[lane] + red8[64 + lane]) + (red8[128 + lane] + red8[192 + lane]))
                   + ((red8[256 + lane] + red8[320 + lane]) + (red8[384 + lane] + red8[448 + lane]));
    cc = cc + LRATE * rl_f(s4, NY);                // gc = -sum(coef); col 50 = ones
    const float gz = s4 - gamma * yhl;
    const float v  = zv - LRATE * gz;

    int ahead = 0; float cs0 = 0.f, cs1 = 0.f;
    #pragma unroll
    for (int k = 0; k < NY; k += 2) {
      const float vk0 = rl_f(v, k);
      const float vk1 = rl_f(v, k + 1);
      const bool b0 = (vk0 > v) || (vk0 == v && (k    ) > lane);
      const bool b1 = (vk1 > v) || (vk1 == v && (k + 1) > lane);
      ahead += (b0 ? 1 : 0) + (b1 ? 1 : 0);
      cs0 += b0 ? vk0 : 0.0f;
      cs1 += b1 ? vk1 : 0.0f;
    }
    const float css = (cs0 + cs1) + v - 1.0f;
    const bool pc = (lane < NY) && (v - css / (float)(ahead + 1) > 0.0f);
    const int rho = __popcll(__ballot(pc));        // >= 1 always
    const unsigned long long bsel = __ballot((lane < NY) && (ahead == rho - 1));
    const int srcl = __ffsll(bsel) - 1;
    const float tau =
        __int_as_float(__builtin_amdgcn_readlane(__float_as_int(css), srcl)) / (float)rho;
    zv = (lane < NY) ? fmaxf(v - tau, 0.0f) : 0.0f;
  }

  if (tid < 64 && lane < NY) out[t * NY + lane] = zv;   // wave 0
}

extern "C" void kernel_launch(void* const* d_in, const int* in_sizes, int n_in,
                              void* d_out, int out_size, void* d_ws, size_t ws_size,
                              hipStream_t stream) {
  (void)in_sizes; (void)n_in; (void)d_ws; (void)ws_size; (void)out_size;
  const float* X   = (const float*)d_in[0];
  const float* Y   = (const float*)d_in[1];
  const float* W   = (const float*)d_in[2];
  const float* B   = (const float*)d_in[3];
  const float* DLT = (const float*)d_in[4];
  const float* GMM = (const float*)d_in[5];
  float* out = (float*)d_out;
  hipLaunchKernelGGL(dro_kernel, dim3(NOBS), dim3(512), 0, stream,
                     X, Y, W, B, DLT, GMM, out);
}

// Round 8
// 1926.033 us; speedup vs baseline: 1.7927x; 1.1951x over previous
//
#include <hip/hip_runtime.h>
#include <cfloat>
#include <math.h>

#define NOBS   256
#define NY     50
#define NX     30
#define NITER  400
#define LRATE  0.05f
#define CSTR   260     // ep_t column stride (floats), init staging
#define THRANK 40      // theta tracks the rank-40 KEY -> C = 41 every valid iter (stable)

__device__ __forceinline__ float rl_f(float x, int k) {
  // v_readlane: SGPR broadcast, no DS-pipe traffic
  return __int_as_float(__builtin_amdgcn_readlane(__float_as_int(x), k));
}
__device__ __forceinline__ unsigned long long rl_u64(unsigned long long x, int k) {
  const unsigned lo = (unsigned)__builtin_amdgcn_readlane((int)(unsigned)(x & 0xffffffffull), k);
  const unsigned hi = (unsigned)__builtin_amdgcn_readlane((int)(unsigned)(x >> 32), k);
  return ((unsigned long long)hi << 32) | lo;
}

// wave64 max: row_shr 1,2,4,8 + row_bcast 15,31; old=x keeps invalid lanes at identity.
#define DPP_MAXSTEP(x, ctrl)                                                       \
  x = fmaxf(x, __int_as_float(__builtin_amdgcn_update_dpp(                         \
        __float_as_int(x), __float_as_int(x), (ctrl), 0xF, 0xF, false)))

// One scenario per block over 8 waves (2/SIMD). tid owns obs (tid&255); half A = waves
// 0-3 (cols 0..24 of er, scan slots 0..31, proj j<25), half B = waves 4-7 (the rest).
// Replication minimized: co-resident waves SERIALIZE replicated VALU work (R7 lesson);
// DS pipe is per-CU & shared by 4 SIMDs -> broadcast b128 scans were ~1.5k cyc/iter.
__global__ __launch_bounds__(512) __attribute__((amdgpu_waves_per_eu(2, 2)))
void dro_kernel(
    const float* __restrict__ X, const float* __restrict__ Y,
    const float* __restrict__ W, const float* __restrict__ Bb,
    const float* __restrict__ DLT, const float* __restrict__ GMM,
    float* __restrict__ out)
{
  __shared__ __align__(16) float ep_t[51 * CSTR];          // init staging (dead after epb load)
  __shared__ __align__(16) unsigned long long rrk[NOBS];   // full keys (fallback scan)
  __shared__ __align__(16) unsigned long long ckey[128];   // candidates [0,C) + sentinels [C,C+64)
  __shared__ __align__(16) float pex[512];                 // fwd half-dots / proj cs partials
  __shared__ __align__(16) int   cex[512];                 // rank half-counts / proj ahead partials
  __shared__ __align__(16) float red8[512];                // 8 per-wave backward partials
  __shared__ float wmax4[4];
  __shared__ int   ccnt[4];
  __shared__ int   wcnt[4];
  __shared__ unsigned long long th_key;

  const int tid  = threadIdx.x;      // 0..511
  const int oid  = tid & 255;        // owned observation
  const int half = tid >> 8;         // 0 = A, 1 = B
  const int lane = tid & 63;
  const int w8   = tid >> 6;         // wave 0..7
  const int wsc  = w8 & 3;           // obs-coverage quarter (obs base wsc*64)
  const int t    = blockIdx.x;       // scenario
  const int jbase = half * 25;

  const float delta = DLT[0];
  const float gamma = GMM[0];
  const float a     = fminf(delta * 0.5f, 255.0f / 256.0f);
  const float a256  = a * 256.0f;

  // ---- init: 25-column slice of owned obs row; stage full ep to LDS for epb ----
  float er[25];
  {
    float xr[NX];
    #pragma unroll
    for (int k = 0; k < NX; ++k) xr[k] = X[oid * NX + k];
    for (int jj = 0; jj < 25; ++jj) {              // W/B wave-uniform -> scalar loads
      const int j = jbase + jj;
      float acc = Bb[j];
      #pragma unroll
      for (int k = 0; k < NX; ++k) acc = fmaf(xr[k], W[j * NX + k], acc);
      const float e = Y[oid * NY + j] - acc;
      er[jj] = e;
      ep_t[j * CSTR + oid] = e;                    // column-major
    }
    if (half == 1) ep_t[NY * CSTR + oid] = 1.0f;   // ones column -> c gradient
  }
  float yhl;                                       // y_hat row t, per-lane copy
  {
    const int jr = (lane < NY) ? lane : 0;
    float acc = Bb[jr];
    #pragma unroll
    for (int k = 0; k < NX; ++k) acc = fmaf(X[t * NX + k], W[jr * NX + k], acc);
    yhl = acc;
    if (tid < NY) out[NOBS * NY + t * NY + tid] = acc;
  }
  if (tid == 0) th_key = ~0ull;                    // iter 0: all candidates -> exact fallback
  __syncthreads();

  // epb: iteration-invariant backward slice in REGISTERS (kills all bwd DS traffic).
  // Wave (half,wsc), lane l: column min(l,50), obs [wsc*64 + half*32, +32).
  float epb[32];
  {
    const int colc = (lane < 51) ? lane : 50;
    const float* ebase = &ep_t[colc * CSTR + wsc * 64 + half * 32];
    #pragma unroll
    for (int q = 0; q < 8; ++q) {
      const float4 e4 = *(const float4*)&ebase[4 * q];
      epb[4*q+0] = e4.x; epb[4*q+1] = e4.y; epb[4*q+2] = e4.z; epb[4*q+3] = e4.w;
    }
  }

  float zv = (lane < NY) ? (1.0f / NY) : 0.0f;     // z one entry/lane, replicated per wave
  float cc = 0.0f;                                 // c, wave-uniform (bitwise identical)

  #pragma unroll 1
  for (int it = 0; it < NITER; ++it) {
    // ---- P0: forward half-dot (25 terms; z via readlane) ----
    const unsigned long long thk = th_key;         // written pre-B5 prev iter -> safe
    float a0 = 0.f, a1 = 0.f, a2 = 0.f, a3 = 0.f;
    #pragma unroll
    for (int jj = 0; jj < 24; jj += 4) {
      a0 = fmaf(er[jj + 0], rl_f(zv, jbase + jj + 0), a0);
      a1 = fmaf(er[jj + 1], rl_f(zv, jbase + jj + 1), a1);
      a2 = fmaf(er[jj + 2], rl_f(zv, jbase + jj + 2), a2);
      a3 = fmaf(er[jj + 3], rl_f(zv, jbase + jj + 3), a3);
    }
    a0 = fmaf(er[24], rl_f(zv, jbase + 24), a0);
    pex[tid] = (a0 + a2) + (a1 + a3);
    __syncthreads();                               // B1: pex (also fences prev-iter proj reads)

    // ---- P1: combine halves -> u,r,key; wave max; candidate ballot ----
    const float u = (pex[oid] + pex[256 + oid]) - cc;   // bitwise identical A/B
    const float r = u * u;
    const unsigned long long key =
        ((unsigned long long)(unsigned)__float_as_int(r) << 32) | (unsigned)oid;
    if (half == 0) rrk[oid] = key;

    float m = r;
    DPP_MAXSTEP(m, 0x111); DPP_MAXSTEP(m, 0x112);
    DPP_MAXSTEP(m, 0x114); DPP_MAXSTEP(m, 0x118);
    DPP_MAXSTEP(m, 0x142); DPP_MAXSTEP(m, 0x143);
    if (w8 < 4 && lane == 63) wmax4[wsc] = m;

    const bool cond = (key <= thk);                // u64-key test: C = THRANK+1 when stable
    const unsigned long long cmask = __ballot(cond);
    const int cpos = __popcll(cmask & ((1ull << lane) - 1ull));
    if (w8 < 4 && lane == 0) ccnt[wsc] = __popcll(cmask);
    __syncthreads();                               // B2: rrk, wmax4, ccnt

    // ---- P2: compaction (A) + sentinels + max ties ----
    const int c0 = ccnt[0], c1 = ccnt[1], c2 = ccnt[2], c3 = ccnt[3];
    const int C  = c0 + c1 + c2 + c3;
    if (half == 0 && C <= 64) {
      const int coff = (wsc > 0 ? c0 : 0) + (wsc > 1 ? c1 : 0) + (wsc > 2 ? c2 : 0);
      if (cond) ckey[coff + cpos] = key;
    }
    if (tid < 64 && C <= 64) ckey[C + tid] = ~0ull;  // sentinels cover [C, C+64) ⊂ [0,128)

    const float mx = fmaxf(fmaxf(wmax4[0], wmax4[1]), fmaxf(wmax4[2], wmax4[3]));
    const bool ismax = (r == mx);
    const unsigned long long mmask = __ballot(ismax);  // all lanes (R3 lesson)
    if (w8 < 4 && lane == 0) wcnt[wsc] = __popcll(mmask);
    __syncthreads();                               // B3: ckey, wcnt

    // ---- P3: half rank-scan via LANE-HELD candidates (1 ds_read_b64/wave, rest readlane) ----
    const bool valid = ((float)C >= a256) && (C <= 64);
    int ch = 0;
    if (__builtin_expect(valid, 1)) {
      const unsigned long long ck = ckey[lane];    // wave holds all 64 slots in lanes
      const int sb = half * 32;                    // A: slots 0..31, B: 32..63
      #pragma unroll
      for (int s = 0; s < 32; ++s) {
        const unsigned long long kj = rl_u64(ck, sb + s);
        ch += (kj < key) ? 1 : 0;                  // sentinels never count
      }
    } else {                                       // iter 0 / drift: exact full scan, halved
      const ulonglong2* p = (const ulonglong2*)&rrk[half * 128];
      #pragma unroll 8
      for (int j = 0; j < 64; ++j) {
        const ulonglong2 kk = p[j];
        ch += (kk.x < key) ? 1 : 0;
        ch += (kk.y < key) ? 1 : 0;
      }
    }
    cex[tid] = ch;
    __syncthreads();                               // B4: cex

    // ---- P4: total rank -> g, coef; backward from epb registers (ZERO DS reads) ----
    const int cnt = cex[oid] + cex[256 + oid];     // exact global stable rank
    const int cm  = wcnt[0] + wcnt[1] + wcnt[2] + wcnt[3];
    // valid mode: rank-40 candidate exists (C=41) and uniquely refreshes theta every iter
    if (half == 0 && cnt == THRANK && (!valid || cond)) th_key = key;
    const float gfac  = fminf(fmaxf((float)cnt + 1.0f - a256, 0.0f), 1.0f) * (1.0f / 256.0f);
    const float g     = gfac + (ismax ? (a / (float)cm) : 0.0f);
    const float coefv = 2.0f * u * g;

    const int lbase = half * 32;                   // coef of obs wsc*64+lbase+q in own lane lbase+q
    float q0 = 0.f, q1 = 0.f, q2 = 0.f, q3 = 0.f;
    #pragma unroll
    for (int q = 0; q < 8; ++q) {
      q0 = fmaf(rl_f(coefv, lbase + 4 * q + 0), epb[4 * q + 0], q0);
      q1 = fmaf(rl_f(coefv, lbase + 4 * q + 1), epb[4 * q + 1], q1);
      q2 = fmaf(rl_f(coefv, lbase + 4 * q + 2), epb[4 * q + 2], q2);
      q3 = fmaf(rl_f(coefv, lbase + 4 * q + 3), epb[4 * q + 3], q3);
    }
    red8[w8 * 64 + lane] = (q0 + q2) + (q1 + q3);
    __syncthreads();                               // B5: red8, th_key

    // ---- P5a: gradient step; SPLIT tau-scan (A: j<25, B: j>=25) ----
    const float s4 = ((red8[lane] + red8[64 + lane]) + (red8[128 + lane] + red8[192 + lane]))
                   + ((red8[256 + lane] + red8[320 + lane]) + (red8[384 + lane] + red8[448 + lane]));
    cc = cc + LRATE * rl_f(s4, NY);                // gc = -sum(coef); col 50 = ones
    const float gz = s4 - gamma * yhl;
    const float v  = zv - LRATE * gz;

    int ahp = 0; float cs0 = 0.f, cs1 = 0.f;
    #pragma unroll
    for (int jj = 0; jj < 25; jj += 2) {           // 13+12 on two accumulators
      const int j0 = jbase + jj;
      const float vk0 = rl_f(v, j0);
      const bool b0 = (vk0 > v) || (vk0 == v && j0 > lane);
      ahp += b0 ? 1 : 0;
      cs0 += b0 ? vk0 : 0.0f;
      if (jj + 1 < 25) {
        const float vk1 = rl_f(v, j0 + 1);
        const bool b1 = (vk1 > v) || (vk1 == v && (j0 + 1) > lane);
        ahp += b1 ? 1 : 0;
        cs1 += b1 ? vk1 : 0.0f;
      }
    }
    pex[tid] = cs0 + cs1;                          // WAR on pex/cex: >=2 barriers since last read
    cex[tid] = ahp;
    __syncthreads();                               // B6: proj partials

    // ---- P5b: combine partials -> tau; z update (small replicated tail) ----
    const int   aheadF = cex[lane] + cex[256 + lane];
    const float csF    = (pex[lane] + pex[256 + lane]) + v - 1.0f;
    const bool pc = (lane < NY) && (v - csF / (float)(aheadF + 1) > 0.0f);
    const int rho = __popcll(__ballot(pc));        // >= 1 always
    const unsigned long long bsel = __ballot((lane < NY) && (aheadF == rho - 1));
    const int srcl = __ffsll(bsel) - 1;
    const float tau =
        __int_as_float(__builtin_amdgcn_readlane(__float_as_int(csF), srcl)) / (float)rho;
    zv = (lane < NY) ? fmaxf(v - tau, 0.0f) : 0.0f;
  }

  if (tid < 64 && lane < NY) out[t * NY + lane] = zv;   // wave 0
}

extern "C" void kernel_launch(void* const* d_in, const int* in_sizes, int n_in,
                              void* d_out, int out_size, void* d_ws, size_t ws_size,
                              hipStream_t stream) {
  (void)in_sizes; (void)n_in; (void)d_ws; (void)ws_size; (void)out_size;
  const float* X   = (const float*)d_in[0];
  const float* Y   = (const float*)d_in[1];
  const float* W   = (const float*)d_in[2];
  const float* B   = (const float*)d_in[3];
  const float* DLT = (const float*)d_in[4];
  const float* GMM = (const float*)d_in[5];
  float* out = (float*)d_out;
  hipLaunchKernelGGL(dro_kernel, dim3(NOBS), dim3(512), 0, stream,
                     X, Y, W, B, DLT, GMM, out);
}